// Round 1
// baseline (863.781 us; speedup 1.0000x reference)
//
#include <hip/hip_runtime.h>
#include <hip/hip_bf16.h>
#include <math.h>

// B=16 L=512 K=48 E=128 D=384 H=128
#define NB 16
#define NL 512
#define NK 48
#define NE 128
#define ND 384
#define NH 128

typedef __attribute__((ext_vector_type(8))) short short8;
typedef __attribute__((ext_vector_type(4))) float f32x4;

__device__ __forceinline__ float gelu_erf(float x) {
    return 0.5f * x * (1.0f + erff(x * 0.70710678118654752f));
}

// round-to-nearest-even f32 -> bf16 bits
__device__ __forceinline__ unsigned short f2bf(float x) {
    union { float f; unsigned u; } v; v.f = x;
    unsigned r = v.u + 0x7fffu + ((v.u >> 16) & 1u);
    return (unsigned short)(r >> 16);
}

// ---------------------------------------------------------------------------
// Kernel 0: pack fw1 [128x384] and fw2 [384x384] into bf16 MFMA-B-fragment
// order: dst[((kt*24+nt)*64 + lane)*8 + j] where lane = ((k>>3)&3)*16 + (n&15),
// j = k&7, kt = k>>5, nt = n>>4.  Also zero the per-batch dG accumulator.
// ---------------------------------------------------------------------------
__global__ void pack_weights(const float* __restrict__ fw1,
                             const float* __restrict__ fw2,
                             unsigned short* __restrict__ fw1p,
                             unsigned short* __restrict__ fw2p,
                             float* __restrict__ dGsum) {
    int tid = blockIdx.x * 256 + threadIdx.x;
    if (tid < NB) dGsum[tid] = 0.0f;
    if (tid < NE * ND) {
        int k = tid / ND, n = tid % ND;
        int kt = k >> 5, quad = (k >> 3) & 3, j = k & 7, nt = n >> 4, nc = n & 15;
        int dst = ((kt * (ND / 16) + nt) * 64 + quad * 16 + nc) * 8 + j;
        fw1p[dst] = f2bf(fw1[tid]);
    } else if (tid < NE * ND + ND * ND) {
        int i = tid - NE * ND;
        int k = i / ND, n = i % ND;
        int kt = k >> 5, quad = (k >> 3) & 3, j = k & 7, nt = n >> 4, nc = n & 15;
        int dst = ((kt * (ND / 16) + nt) * 64 + quad * 16 + nc) * 8 + j;
        fw2p[dst] = f2bf(fw2[i]);
    }
}

// ---------------------------------------------------------------------------
// Kernel 1: fused CFConv.  One block = 2 (b,l) groups = 96 edge-rows.
// GEMM1 [96x128]@[128x384] -> gelu -> bf16 T (LDS) -> GEMM2 [96x384]@[384x384]
// epilogue: bias+gelu -> W, gather x_j = h_V[E_idx], reduce over k -> h[b,l,:]
// ---------------------------------------------------------------------------
__global__ __launch_bounds__(256, 2) void cfconv_kernel(
    const float* __restrict__ h_V, const float* __restrict__ h_E,
    const float* __restrict__ fb1, const float* __restrict__ fb2,
    const unsigned short* __restrict__ fw1p,
    const unsigned short* __restrict__ fw2p,
    const int* __restrict__ E_idx, float* __restrict__ hbuf)
{
    __shared__ unsigned short smem[96 * 392];  // T (stride 392); head aliased as Ea (stride 136)
    __shared__ int rowoff_s[96];

    const int t = threadIdx.x;
    const int wave = t >> 6, lane = t & 63;
    const int quad = lane >> 4, l16 = lane & 15;
    const int bl0 = blockIdx.x * 2;
    const int wn0 = wave * 96;   // this wave's column base (384 / 4 waves)

    // E_idx -> precomputed h_V row offsets
    if (t < 96) {
        int g = t / 48, k = t - g * 48;
        int bl = bl0 + g;
        int idx = E_idx[bl * NK + k];
        rowoff_s[t] = ((bl >> 9) * NL + idx) * ND;
    }

    // stage h_E (2 groups, 96x128 f32) -> bf16 LDS rows (stride 136)
    {
        const float4* src = (const float4*)(h_E + (size_t)bl0 * (NK * NE));
        #pragma unroll
        for (int i = 0; i < 12; i++) {
            int v = i * 256 + t;         // 3072 float4
            float4 d = src[v];
            int r = v >> 5;              // 32 float4 per 128-col row
            int c = (v & 31) * 4;
            ushort4 u;
            u.x = f2bf(d.x); u.y = f2bf(d.y); u.z = f2bf(d.z); u.w = f2bf(d.w);
            *(ushort4*)&smem[r * 136 + c] = u;
        }
    }
    __syncthreads();

    f32x4 acc[6][6];

    // ---- GEMM1: K = 128 (4 k-steps) ----
    #pragma unroll
    for (int mt = 0; mt < 6; mt++)
        #pragma unroll
        for (int nt = 0; nt < 6; nt++)
            acc[mt][nt] = (f32x4){0.f, 0.f, 0.f, 0.f};

    #pragma unroll
    for (int kt = 0; kt < 4; kt++) {
        short8 bfrag[6], afrag[6];
        #pragma unroll
        for (int nt = 0; nt < 6; nt++)
            bfrag[nt] = *(const short8*)(fw1p + (size_t)((kt * 24 + (wn0 >> 4) + nt) * 64 + lane) * 8);
        #pragma unroll
        for (int mt = 0; mt < 6; mt++)
            afrag[mt] = *(const short8*)&smem[(mt * 16 + l16) * 136 + kt * 32 + quad * 8];
        #pragma unroll
        for (int mt = 0; mt < 6; mt++)
            #pragma unroll
            for (int nt = 0; nt < 6; nt++)
                acc[mt][nt] = __builtin_amdgcn_mfma_f32_16x16x32_bf16(
                    afrag[mt], bfrag[nt], acc[mt][nt], 0, 0, 0);
    }
    __syncthreads();  // all waves done reading Ea; smem becomes T

    // epilogue1: +fb1, gelu, -> bf16 T (stride 392)
    #pragma unroll
    for (int nt = 0; nt < 6; nt++) {
        int col = wn0 + nt * 16 + l16;
        float b1 = fb1[col];
        #pragma unroll
        for (int mt = 0; mt < 6; mt++) {
            int rowb = mt * 16 + quad * 4;
            #pragma unroll
            for (int r = 0; r < 4; r++)
                smem[(rowb + r) * 392 + col] = f2bf(gelu_erf(acc[mt][nt][r] + b1));
        }
    }
    __syncthreads();

    // ---- GEMM2: K = 384 (12 k-steps) ----
    #pragma unroll
    for (int mt = 0; mt < 6; mt++)
        #pragma unroll
        for (int nt = 0; nt < 6; nt++)
            acc[mt][nt] = (f32x4){0.f, 0.f, 0.f, 0.f};

    for (int kt = 0; kt < 12; kt++) {
        short8 bfrag[6], afrag[6];
        #pragma unroll
        for (int nt = 0; nt < 6; nt++)
            bfrag[nt] = *(const short8*)(fw2p + (size_t)((kt * 24 + (wn0 >> 4) + nt) * 64 + lane) * 8);
        #pragma unroll
        for (int mt = 0; mt < 6; mt++)
            afrag[mt] = *(const short8*)&smem[(mt * 16 + l16) * 392 + kt * 32 + quad * 8];
        #pragma unroll
        for (int mt = 0; mt < 6; mt++)
            #pragma unroll
            for (int nt = 0; nt < 6; nt++)
                acc[mt][nt] = __builtin_amdgcn_mfma_f32_16x16x32_bf16(
                    afrag[mt], bfrag[nt], acc[mt][nt], 0, 0, 0);
    }

    // epilogue2: +fb2, gelu -> W; gather x_j; reduce over k (rows); store h
    #pragma unroll
    for (int g = 0; g < 2; g++) {
        #pragma unroll
        for (int nt = 0; nt < 6; nt++) {
            int col = wn0 + nt * 16 + l16;
            float b2 = fb2[col];
            float s = 0.f;
            #pragma unroll
            for (int mt = g * 3; mt < g * 3 + 3; mt++) {
                int rowb = mt * 16 + quad * 4;
                #pragma unroll
                for (int r = 0; r < 4; r++) {
                    float w = gelu_erf(acc[mt][nt][r] + b2);
                    float xj = h_V[rowoff_s[rowb + r] + col];
                    s += w * xj;
                }
            }
            s += __shfl_xor(s, 16, 64);
            s += __shfl_xor(s, 32, 64);
            if (lane < 16)
                hbuf[(size_t)(bl0 + g) * ND + wn0 + nt * 16 + lane] = s;
        }
    }
}

// ---------------------------------------------------------------------------
// Kernel 2: MLP head (fp32) over 16 rows per block + masked per-batch sum
// ---------------------------------------------------------------------------
__global__ __launch_bounds__(256) void head_kernel(
    const float* __restrict__ hbuf,
    const float* __restrict__ hw1, const float* __restrict__ hb1,
    const float* __restrict__ hw2, const float* __restrict__ hb2,
    const float* __restrict__ hw3, const float* __restrict__ hb3,
    const float* __restrict__ mask, float* __restrict__ dGsum)
{
    __shared__ float hs[16][388];
    __shared__ float g1[16][132];
    __shared__ float g2[16][68];
    const int t = threadIdx.x;
    const int row0 = blockIdx.x * 16;

    const float4* src = (const float4*)(hbuf + (size_t)row0 * ND);
    #pragma unroll
    for (int i = 0; i < 6; i++) {
        int v = i * 256 + t;      // 1536 float4 = 16 x 384
        float4 d = src[v];
        int r = v / 96;
        int c = (v % 96) * 4;
        *(float4*)&hs[r][c] = d;
    }
    __syncthreads();

    // layer1: 384 -> 128, thread = (row, 8-col strip)
    {
        int r = t >> 4, cb = (t & 15) * 8;
        float a[8];
        #pragma unroll
        for (int i = 0; i < 8; i++) a[i] = hb1[cb + i];
        for (int k = 0; k < 384; k++) {
            float x = hs[r][k];
            const float* wrow = hw1 + k * 128 + cb;
            #pragma unroll
            for (int i = 0; i < 8; i++) a[i] += x * wrow[i];
        }
        #pragma unroll
        for (int i = 0; i < 8; i++) g1[r][cb + i] = gelu_erf(a[i]);
    }
    __syncthreads();

    // layer2: 128 -> 64, thread = (row, 4-col strip)
    {
        int r = t >> 4, cb = (t & 15) * 4;
        float a[4];
        #pragma unroll
        for (int i = 0; i < 4; i++) a[i] = hb2[cb + i];
        for (int k = 0; k < 128; k++) {
            float x = g1[r][k];
            const float* wrow = hw2 + k * 64 + cb;
            #pragma unroll
            for (int i = 0; i < 4; i++) a[i] += x * wrow[i];
        }
        #pragma unroll
        for (int i = 0; i < 4; i++) g2[r][cb + i] = gelu_erf(a[i]);
    }
    __syncthreads();

    // layer3: 64 -> 1, then masked per-batch accumulation
    {
        int r = t >> 4, j = t & 15;
        float s = 0.f;
        #pragma unroll
        for (int k = 0; k < 4; k++) s += g2[r][j + k * 16] * hw3[j + k * 16];
        s += __shfl_xor(s, 1, 64);
        s += __shfl_xor(s, 2, 64);
        s += __shfl_xor(s, 4, 64);
        s += __shfl_xor(s, 8, 64);
        if (j == 0) {
            int bl = row0 + r;
            atomicAdd(&dGsum[bl >> 9], (s + hb3[0]) * mask[bl]);
        }
    }
}

// ---------------------------------------------------------------------------
// Kernel 3: out[b] = dGsum[b] / sqrt(clip(sum(mask[b,:]), 1))
// ---------------------------------------------------------------------------
__global__ void finalize_kernel(const float* __restrict__ dGsum,
                                const float* __restrict__ mask,
                                float* __restrict__ out) {
    int b = threadIdx.x;
    if (b < NB) {
        float ms = 0.f;
        for (int l = 0; l < NL; l++) ms += mask[b * NL + l];
        ms = fmaxf(ms, 1.0f);
        out[b] = dGsum[b] / sqrtf(ms);
    }
}

extern "C" void kernel_launch(void* const* d_in, const int* in_sizes, int n_in,
                              void* d_out, int out_size, void* d_ws, size_t ws_size,
                              hipStream_t stream) {
    const float* h_V  = (const float*)d_in[0];
    const float* h_E  = (const float*)d_in[1];
    const float* mask = (const float*)d_in[2];
    const float* fw1  = (const float*)d_in[3];
    const float* fb1  = (const float*)d_in[4];
    const float* fw2  = (const float*)d_in[5];
    const float* fb2  = (const float*)d_in[6];
    const float* hw1  = (const float*)d_in[7];
    const float* hb1  = (const float*)d_in[8];
    const float* hw2  = (const float*)d_in[9];
    const float* hb2  = (const float*)d_in[10];
    const float* hw3  = (const float*)d_in[11];
    const float* hb3  = (const float*)d_in[12];
    const int*   E_idx = (const int*)d_in[13];
    float* out = (float*)d_out;

    char* ws = (char*)d_ws;
    unsigned short* fw1p = (unsigned short*)ws;             // 128*384*2 = 98304 B
    unsigned short* fw2p = (unsigned short*)(ws + 98304);   // 384*384*2 = 294912 B
    float* dGsum = (float*)(ws + 393216);                   // 64 B
    float* hbuf  = (float*)(ws + 393472);                   // 8192*384*4 = 12.6 MB

    pack_weights<<<768, 256, 0, stream>>>(fw1, fw2, fw1p, fw2p, dGsum);
    cfconv_kernel<<<(NB * NL) / 2, 256, 0, stream>>>(h_V, h_E, fb1, fb2, fw1p, fw2p, E_idx, hbuf);
    head_kernel<<<(NB * NL) / 16, 256, 0, stream>>>(hbuf, hw1, hb1, hw2, hb2, hw3, hb3, mask, dGsum);
    finalize_kernel<<<1, 64, 0, stream>>>(dGsum, mask, out);
}

// Round 2
// 639.779 us; speedup vs baseline: 1.3501x; 1.3501x over previous
//
#include <hip/hip_runtime.h>
#include <hip/hip_bf16.h>
#include <math.h>

// B=16 L=512 K=48 E=128 D=384 H=128
#define NB 16
#define NL 512
#define NK 48
#define NE 128
#define ND 384
#define NH 128

typedef __attribute__((ext_vector_type(8))) short short8;
typedef __attribute__((ext_vector_type(4))) float f32x4;

// fast erf-gelu: tanh-form reduced to sigmoid, sigmoid via hw exp2 + rcp.
// g = x * sigmoid(1.5957691*x + 0.0713549*x^3)
//   = x / (1 + exp2(x*(-2.3022087 - 0.1029437*x^2)))
// max abs err vs erf-gelu ~3e-4; saturation-safe at large |x|.
__device__ __forceinline__ float gelu_fast(float x) {
    float t = x * fmaf(x * x, -0.1029437f, -2.3022087f);
    float e = __builtin_amdgcn_exp2f(t);
    return x * __builtin_amdgcn_rcpf(1.0f + e);
}

// round-to-nearest-even f32 -> bf16 bits
__device__ __forceinline__ unsigned short f2bf(float x) {
    union { float f; unsigned u; } v; v.f = x;
    unsigned r = v.u + 0x7fffu + ((v.u >> 16) & 1u);
    return (unsigned short)(r >> 16);
}

// ---------------------------------------------------------------------------
// Kernel 0: pack fw1 [128x384] and fw2 [384x384] into bf16 MFMA-B-fragment
// order: dst[((kt*24+nt)*64 + lane)*8 + j] where lane = ((k>>3)&3)*16 + (n&15),
// j = k&7, kt = k>>5, nt = n>>4.  Also zero the per-batch dG accumulator.
// ---------------------------------------------------------------------------
__global__ void pack_weights(const float* __restrict__ fw1,
                             const float* __restrict__ fw2,
                             unsigned short* __restrict__ fw1p,
                             unsigned short* __restrict__ fw2p,
                             float* __restrict__ dGsum) {
    int tid = blockIdx.x * 256 + threadIdx.x;
    if (tid < NB) dGsum[tid] = 0.0f;
    if (tid < NE * ND) {
        int k = tid / ND, n = tid % ND;
        int kt = k >> 5, quad = (k >> 3) & 3, j = k & 7, nt = n >> 4, nc = n & 15;
        int dst = ((kt * (ND / 16) + nt) * 64 + quad * 16 + nc) * 8 + j;
        fw1p[dst] = f2bf(fw1[tid]);
    } else if (tid < NE * ND + ND * ND) {
        int i = tid - NE * ND;
        int k = i / ND, n = i % ND;
        int kt = k >> 5, quad = (k >> 3) & 3, j = k & 7, nt = n >> 4, nc = n & 15;
        int dst = ((kt * (ND / 16) + nt) * 64 + quad * 16 + nc) * 8 + j;
        fw2p[dst] = f2bf(fw2[i]);
    }
}

// ---------------------------------------------------------------------------
// Kernel 1: fused CFConv.  One block = 2 (b,l) groups = 96 edge-rows.
// GEMM1 [96x128]@[128x384] -> gelu -> bf16 T (LDS) -> GEMM2 [96x384]@[384x384]
// epilogue: bias+gelu -> W, gather x_j = h_V[E_idx], reduce over k -> h[b,l,:]
// ---------------------------------------------------------------------------
__global__ __launch_bounds__(256, 2) void cfconv_kernel(
    const float* __restrict__ h_V, const float* __restrict__ h_E,
    const float* __restrict__ fb1, const float* __restrict__ fb2,
    const unsigned short* __restrict__ fw1p,
    const unsigned short* __restrict__ fw2p,
    const int* __restrict__ E_idx, float* __restrict__ hbuf)
{
    __shared__ unsigned short smem[96 * 392];  // T (stride 392); head aliased as Ea (stride 136)
    __shared__ int rowoff_s[96];

    const int t = threadIdx.x;
    const int wave = t >> 6, lane = t & 63;
    const int quad = lane >> 4, l16 = lane & 15;
    const int bl0 = blockIdx.x * 2;
    const int wn0 = wave * 96;   // this wave's column base (384 / 4 waves)

    // E_idx -> precomputed h_V row offsets
    if (t < 96) {
        int g = t / 48, k = t - g * 48;
        int bl = bl0 + g;
        int idx = E_idx[bl * NK + k];
        rowoff_s[t] = ((bl >> 9) * NL + idx) * ND;
    }

    // stage h_E (2 groups, 96x128 f32) -> bf16 LDS rows (stride 136)
    {
        const float4* src = (const float4*)(h_E + (size_t)bl0 * (NK * NE));
        #pragma unroll
        for (int i = 0; i < 12; i++) {
            int v = i * 256 + t;         // 3072 float4
            float4 d = src[v];
            int r = v >> 5;              // 32 float4 per 128-col row
            int c = (v & 31) * 4;
            ushort4 u;
            u.x = f2bf(d.x); u.y = f2bf(d.y); u.z = f2bf(d.z); u.w = f2bf(d.w);
            *(ushort4*)&smem[r * 136 + c] = u;
        }
    }
    __syncthreads();

    f32x4 acc[6][6];

    // ---- GEMM1: K = 128 (4 k-steps) ----
    #pragma unroll
    for (int mt = 0; mt < 6; mt++)
        #pragma unroll
        for (int nt = 0; nt < 6; nt++)
            acc[mt][nt] = (f32x4){0.f, 0.f, 0.f, 0.f};

    #pragma unroll
    for (int kt = 0; kt < 4; kt++) {
        short8 bfrag[6], afrag[6];
        #pragma unroll
        for (int nt = 0; nt < 6; nt++)
            bfrag[nt] = *(const short8*)(fw1p + (size_t)((kt * 24 + (wn0 >> 4) + nt) * 64 + lane) * 8);
        #pragma unroll
        for (int mt = 0; mt < 6; mt++)
            afrag[mt] = *(const short8*)&smem[(mt * 16 + l16) * 136 + kt * 32 + quad * 8];
        #pragma unroll
        for (int mt = 0; mt < 6; mt++)
            #pragma unroll
            for (int nt = 0; nt < 6; nt++)
                acc[mt][nt] = __builtin_amdgcn_mfma_f32_16x16x32_bf16(
                    afrag[mt], bfrag[nt], acc[mt][nt], 0, 0, 0);
    }
    __syncthreads();  // all waves done reading Ea; smem becomes T

    // epilogue1: +fb1, gelu, -> bf16 T (stride 392)
    #pragma unroll
    for (int nt = 0; nt < 6; nt++) {
        int col = wn0 + nt * 16 + l16;
        float b1 = fb1[col];
        #pragma unroll
        for (int mt = 0; mt < 6; mt++) {
            int rowb = mt * 16 + quad * 4;
            #pragma unroll
            for (int r = 0; r < 4; r++)
                smem[(rowb + r) * 392 + col] = f2bf(gelu_fast(acc[mt][nt][r] + b1));
        }
    }
    __syncthreads();

    // ---- GEMM2: K = 384 (12 k-steps) ----
    #pragma unroll
    for (int mt = 0; mt < 6; mt++)
        #pragma unroll
        for (int nt = 0; nt < 6; nt++)
            acc[mt][nt] = (f32x4){0.f, 0.f, 0.f, 0.f};

    for (int kt = 0; kt < 12; kt++) {
        short8 bfrag[6], afrag[6];
        #pragma unroll
        for (int nt = 0; nt < 6; nt++)
            bfrag[nt] = *(const short8*)(fw2p + (size_t)((kt * 24 + (wn0 >> 4) + nt) * 64 + lane) * 8);
        #pragma unroll
        for (int mt = 0; mt < 6; mt++)
            afrag[mt] = *(const short8*)&smem[(mt * 16 + l16) * 392 + kt * 32 + quad * 8];
        #pragma unroll
        for (int mt = 0; mt < 6; mt++)
            #pragma unroll
            for (int nt = 0; nt < 6; nt++)
                acc[mt][nt] = __builtin_amdgcn_mfma_f32_16x16x32_bf16(
                    afrag[mt], bfrag[nt], acc[mt][nt], 0, 0, 0);
    }

    // epilogue2: +fb2, gelu -> W; gather x_j; reduce over k (rows); store h
    #pragma unroll
    for (int g = 0; g < 2; g++) {
        #pragma unroll
        for (int nt = 0; nt < 6; nt++) {
            int col = wn0 + nt * 16 + l16;
            float b2 = fb2[col];
            float s = 0.f;
            #pragma unroll
            for (int mt = g * 3; mt < g * 3 + 3; mt++) {
                int rowb = mt * 16 + quad * 4;
                #pragma unroll
                for (int r = 0; r < 4; r++) {
                    float w = gelu_fast(acc[mt][nt][r] + b2);
                    float xj = h_V[rowoff_s[rowb + r] + col];
                    s += w * xj;
                }
            }
            s += __shfl_xor(s, 16, 64);
            s += __shfl_xor(s, 32, 64);
            if (lane < 16)
                hbuf[(size_t)(bl0 + g) * ND + wn0 + nt * 16 + lane] = s;
        }
    }
}

// ---------------------------------------------------------------------------
// Kernel 2: MLP head (fp32) over 16 rows per block + masked per-batch sum
// ---------------------------------------------------------------------------
__global__ __launch_bounds__(256) void head_kernel(
    const float* __restrict__ hbuf,
    const float* __restrict__ hw1, const float* __restrict__ hb1,
    const float* __restrict__ hw2, const float* __restrict__ hb2,
    const float* __restrict__ hw3, const float* __restrict__ hb3,
    const float* __restrict__ mask, float* __restrict__ dGsum)
{
    __shared__ float hs[16][388];
    __shared__ float g1[16][132];
    __shared__ float g2[16][68];
    const int t = threadIdx.x;
    const int row0 = blockIdx.x * 16;

    const float4* src = (const float4*)(hbuf + (size_t)row0 * ND);
    #pragma unroll
    for (int i = 0; i < 6; i++) {
        int v = i * 256 + t;      // 1536 float4 = 16 x 384
        float4 d = src[v];
        int r = v / 96;
        int c = (v % 96) * 4;
        *(float4*)&hs[r][c] = d;
    }
    __syncthreads();

    // layer1: 384 -> 128, thread = (row, 8-col strip)
    {
        int r = t >> 4, cb = (t & 15) * 8;
        float a[8];
        #pragma unroll
        for (int i = 0; i < 8; i++) a[i] = hb1[cb + i];
        for (int k = 0; k < 384; k++) {
            float x = hs[r][k];
            const float* wrow = hw1 + k * 128 + cb;
            #pragma unroll
            for (int i = 0; i < 8; i++) a[i] += x * wrow[i];
        }
        #pragma unroll
        for (int i = 0; i < 8; i++) g1[r][cb + i] = gelu_fast(a[i]);
    }
    __syncthreads();

    // layer2: 128 -> 64, thread = (row, 4-col strip)
    {
        int r = t >> 4, cb = (t & 15) * 4;
        float a[4];
        #pragma unroll
        for (int i = 0; i < 4; i++) a[i] = hb2[cb + i];
        for (int k = 0; k < 128; k++) {
            float x = g1[r][k];
            const float* wrow = hw2 + k * 64 + cb;
            #pragma unroll
            for (int i = 0; i < 4; i++) a[i] += x * wrow[i];
        }
        #pragma unroll
        for (int i = 0; i < 4; i++) g2[r][cb + i] = gelu_fast(a[i]);
    }
    __syncthreads();

    // layer3: 64 -> 1, then masked per-batch accumulation
    {
        int r = t >> 4, j = t & 15;
        float s = 0.f;
        #pragma unroll
        for (int k = 0; k < 4; k++) s += g2[r][j + k * 16] * hw3[j + k * 16];
        s += __shfl_xor(s, 1, 64);
        s += __shfl_xor(s, 2, 64);
        s += __shfl_xor(s, 4, 64);
        s += __shfl_xor(s, 8, 64);
        if (j == 0) {
            int bl = row0 + r;
            atomicAdd(&dGsum[bl >> 9], (s + hb3[0]) * mask[bl]);
        }
    }
}

// ---------------------------------------------------------------------------
// Kernel 3: out[b] = dGsum[b] / sqrt(clip(sum(mask[b,:]), 1))
// one block, 256 threads: 16 lanes per batch
// ---------------------------------------------------------------------------
__global__ void finalize_kernel(const float* __restrict__ dGsum,
                                const float* __restrict__ mask,
                                float* __restrict__ out) {
    int t = threadIdx.x;
    int b = t >> 4, j = t & 15;
    float ms = 0.f;
    for (int l = j; l < NL; l += 16) ms += mask[b * NL + l];
    ms += __shfl_xor(ms, 1, 64);
    ms += __shfl_xor(ms, 2, 64);
    ms += __shfl_xor(ms, 4, 64);
    ms += __shfl_xor(ms, 8, 64);
    if (j == 0) {
        ms = fmaxf(ms, 1.0f);
        out[b] = dGsum[b] / sqrtf(ms);
    }
}

extern "C" void kernel_launch(void* const* d_in, const int* in_sizes, int n_in,
                              void* d_out, int out_size, void* d_ws, size_t ws_size,
                              hipStream_t stream) {
    const float* h_V  = (const float*)d_in[0];
    const float* h_E  = (const float*)d_in[1];
    const float* mask = (const float*)d_in[2];
    const float* fw1  = (const float*)d_in[3];
    const float* fb1  = (const float*)d_in[4];
    const float* fw2  = (const float*)d_in[5];
    const float* fb2  = (const float*)d_in[6];
    const float* hw1  = (const float*)d_in[7];
    const float* hb1  = (const float*)d_in[8];
    const float* hw2  = (const float*)d_in[9];
    const float* hb2  = (const float*)d_in[10];
    const float* hw3  = (const float*)d_in[11];
    const float* hb3  = (const float*)d_in[12];
    const int*   E_idx = (const int*)d_in[13];
    float* out = (float*)d_out;

    char* ws = (char*)d_ws;
    unsigned short* fw1p = (unsigned short*)ws;             // 128*384*2 = 98304 B
    unsigned short* fw2p = (unsigned short*)(ws + 98304);   // 384*384*2 = 294912 B
    float* dGsum = (float*)(ws + 393216);                   // 64 B
    float* hbuf  = (float*)(ws + 393472);                   // 8192*384*4 = 12.6 MB

    pack_weights<<<768, 256, 0, stream>>>(fw1, fw2, fw1p, fw2p, dGsum);
    cfconv_kernel<<<(NB * NL) / 2, 256, 0, stream>>>(h_V, h_E, fb1, fb2, fw1p, fw2p, E_idx, hbuf);
    head_kernel<<<(NB * NL) / 16, 256, 0, stream>>>(hbuf, hw1, hb1, hw2, hb2, hw3, hb3, mask, dGsum);
    finalize_kernel<<<1, 256, 0, stream>>>(dGsum, mask, out);
}

// Round 3
// 501.238 us; speedup vs baseline: 1.7233x; 1.2764x over previous
//
#include <hip/hip_runtime.h>
#include <hip/hip_bf16.h>
#include <math.h>

// B=16 L=512 K=48 E=128 D=384 H=128
#define NB 16
#define NL 512
#define NK 48
#define NE 128
#define ND 384
#define NH 128

typedef __attribute__((ext_vector_type(8))) short short8;
typedef __attribute__((ext_vector_type(4))) float f32x4;

// fast erf-gelu: tanh-form reduced to sigmoid, sigmoid via hw exp2 + rcp.
__device__ __forceinline__ float gelu_fast(float x) {
    float t = x * fmaf(x * x, -0.1029437f, -2.3022087f);
    float e = __builtin_amdgcn_exp2f(t);
    return x * __builtin_amdgcn_rcpf(1.0f + e);
}

// round-to-nearest-even f32 -> bf16 bits (used in pack, once per launch)
__device__ __forceinline__ unsigned short f2bf(float x) {
    union { float f; unsigned u; } v; v.f = x;
    unsigned r = v.u + 0x7fffu + ((v.u >> 16) & 1u);
    return (unsigned short)(r >> 16);
}

// cheap round-half-up f32 -> bf16 bits (2 inst)
__device__ __forceinline__ unsigned short f2bf_rhu(float x) {
    union { float f; unsigned u; } v; v.f = x;
    return (unsigned short)((v.u + 0x8000u) >> 16);
}

// pack two f32 -> (bf16(a)<<16)|bf16(b), round-half-up: 2 adds + 1 v_perm
__device__ __forceinline__ unsigned pk_bf16(float a, float b) {
    union { float f; unsigned u; } ua, ub; ua.f = a; ub.f = b;
    return __builtin_amdgcn_perm(ua.u + 0x8000u, ub.u + 0x8000u, 0x07060302u);
}

// ---------------------------------------------------------------------------
// Kernel 0: pack fw1/fw2/hw1/hw2 into bf16 MFMA-B-fragment order:
// dst[((kt*NT+nt)*64 + quad*16 + nc)*8 + j], kt=k>>5, quad=(k>>3)&3, j=k&7,
// nt=n>>4, nc=n&15.  Also zero the per-batch dG accumulator.
// ---------------------------------------------------------------------------
__global__ void pack_weights(const float* __restrict__ fw1,
                             const float* __restrict__ fw2,
                             const float* __restrict__ hw1,
                             const float* __restrict__ hw2,
                             unsigned short* __restrict__ fw1p,
                             unsigned short* __restrict__ fw2p,
                             unsigned short* __restrict__ hw1p,
                             unsigned short* __restrict__ hw2p,
                             float* __restrict__ dGsum) {
    int tid = blockIdx.x * 256 + threadIdx.x;
    if (tid < NB) dGsum[tid] = 0.0f;
    if (tid < NE * ND) {                                  // fw1 128x384
        int k = tid / ND, n = tid % ND;
        int dst = (((k >> 5) * 24 + (n >> 4)) * 64 + ((k >> 3) & 3) * 16 + (n & 15)) * 8 + (k & 7);
        fw1p[dst] = f2bf(fw1[tid]);
    } else if (tid < NE * ND + ND * ND) {                 // fw2 384x384
        int i = tid - NE * ND;
        int k = i / ND, n = i % ND;
        int dst = (((k >> 5) * 24 + (n >> 4)) * 64 + ((k >> 3) & 3) * 16 + (n & 15)) * 8 + (k & 7);
        fw2p[dst] = f2bf(fw2[i]);
    } else if (tid < NE * ND + ND * ND + ND * NH) {       // hw1 384x128
        int i = tid - (NE * ND + ND * ND);
        int k = i / NH, n = i % NH;
        int dst = (((k >> 5) * 8 + (n >> 4)) * 64 + ((k >> 3) & 3) * 16 + (n & 15)) * 8 + (k & 7);
        hw1p[dst] = f2bf(hw1[i]);
    } else if (tid < NE * ND + ND * ND + ND * NH + NH * (NH / 2)) {  // hw2 128x64
        int i = tid - (NE * ND + ND * ND + ND * NH);
        int k = i / (NH / 2), n = i % (NH / 2);
        int dst = (((k >> 5) * 4 + (n >> 4)) * 64 + ((k >> 3) & 3) * 16 + (n & 15)) * 8 + (k & 7);
        hw2p[dst] = f2bf(hw2[i]);
    }
}

// ---------------------------------------------------------------------------
// Kernel 1: fused CFConv.  One block = 2 (b,l) groups = 96 edge-rows.
// GEMM1 [96x128]@[128x384] -> gelu -> bf16 T (LDS) -> GEMM2 [96x384]@[384x384]
// epilogue: bias+gelu -> W, gather x_j = h_V[E_idx], reduce over k -> h[b,l,:]
// output h written as bf16 row-major (A-fragment-ready for head_kernel).
// ---------------------------------------------------------------------------
__global__ __launch_bounds__(256, 2) void cfconv_kernel(
    const float* __restrict__ h_V, const float* __restrict__ h_E,
    const float* __restrict__ fb1, const float* __restrict__ fb2,
    const unsigned short* __restrict__ fw1p,
    const unsigned short* __restrict__ fw2p,
    const int* __restrict__ E_idx, unsigned short* __restrict__ hbufB)
{
    __shared__ unsigned short smem[96 * 392];  // T (stride 392); head aliased as Ea (stride 136)
    __shared__ int rowoff_s[96];

    const int t = threadIdx.x;
    const int wave = t >> 6, lane = t & 63;
    const int quad = lane >> 4, l16 = lane & 15;
    const int bl0 = blockIdx.x * 2;
    const int wn0 = wave * 96;   // this wave's column base (384 / 4 waves)

    // E_idx -> precomputed h_V row offsets
    if (t < 96) {
        int g = t / 48, k = t - g * 48;
        int bl = bl0 + g;
        int idx = E_idx[bl * NK + k];
        rowoff_s[t] = ((bl >> 9) * NL + idx) * ND;
    }

    // stage h_E (2 groups, 96x128 f32) -> bf16 LDS rows (stride 136)
    {
        const float4* src = (const float4*)(h_E + (size_t)bl0 * (NK * NE));
        #pragma unroll
        for (int i = 0; i < 12; i++) {
            int v = i * 256 + t;         // 3072 float4
            float4 d = src[v];
            int r = v >> 5;              // 32 float4 per 128-col row
            int c = (v & 31) * 4;
            uint2 u;
            u.x = pk_bf16(d.y, d.x);
            u.y = pk_bf16(d.w, d.z);
            *(uint2*)&smem[r * 136 + c] = u;
        }
    }
    __syncthreads();

    f32x4 acc[6][6];

    // ---- GEMM1: K = 128 (4 k-steps) ----
    #pragma unroll
    for (int mt = 0; mt < 6; mt++)
        #pragma unroll
        for (int nt = 0; nt < 6; nt++)
            acc[mt][nt] = (f32x4){0.f, 0.f, 0.f, 0.f};

    #pragma unroll
    for (int kt = 0; kt < 4; kt++) {
        short8 bfrag[6], afrag[6];
        #pragma unroll
        for (int nt = 0; nt < 6; nt++)
            bfrag[nt] = *(const short8*)(fw1p + (size_t)((kt * 24 + (wn0 >> 4) + nt) * 64 + lane) * 8);
        #pragma unroll
        for (int mt = 0; mt < 6; mt++)
            afrag[mt] = *(const short8*)&smem[(mt * 16 + l16) * 136 + kt * 32 + quad * 8];
        #pragma unroll
        for (int mt = 0; mt < 6; mt++)
            #pragma unroll
            for (int nt = 0; nt < 6; nt++)
                acc[mt][nt] = __builtin_amdgcn_mfma_f32_16x16x32_bf16(
                    afrag[mt], bfrag[nt], acc[mt][nt], 0, 0, 0);
    }
    __syncthreads();  // all waves done reading Ea; smem becomes T

    // epilogue1: +fb1, gelu, -> bf16 T (stride 392)
    #pragma unroll
    for (int nt = 0; nt < 6; nt++) {
        int col = wn0 + nt * 16 + l16;
        float b1 = fb1[col];
        #pragma unroll
        for (int mt = 0; mt < 6; mt++) {
            int rowb = mt * 16 + quad * 4;
            #pragma unroll
            for (int r = 0; r < 4; r++)
                smem[(rowb + r) * 392 + col] = f2bf_rhu(gelu_fast(acc[mt][nt][r] + b1));
        }
    }
    __syncthreads();

    // ---- GEMM2: K = 384 (12 k-steps) ----
    #pragma unroll
    for (int mt = 0; mt < 6; mt++)
        #pragma unroll
        for (int nt = 0; nt < 6; nt++)
            acc[mt][nt] = (f32x4){0.f, 0.f, 0.f, 0.f};

    for (int kt = 0; kt < 12; kt++) {
        short8 bfrag[6], afrag[6];
        #pragma unroll
        for (int nt = 0; nt < 6; nt++)
            bfrag[nt] = *(const short8*)(fw2p + (size_t)((kt * 24 + (wn0 >> 4) + nt) * 64 + lane) * 8);
        #pragma unroll
        for (int mt = 0; mt < 6; mt++)
            afrag[mt] = *(const short8*)&smem[(mt * 16 + l16) * 392 + kt * 32 + quad * 8];
        #pragma unroll
        for (int mt = 0; mt < 6; mt++)
            #pragma unroll
            for (int nt = 0; nt < 6; nt++)
                acc[mt][nt] = __builtin_amdgcn_mfma_f32_16x16x32_bf16(
                    afrag[mt], bfrag[nt], acc[mt][nt], 0, 0, 0);
    }

    // hoist biases
    float b2v[6];
    #pragma unroll
    for (int nt = 0; nt < 6; nt++) b2v[nt] = fb2[wn0 + nt * 16 + l16];

    // epilogue2: +fb2, gelu -> W; gather x_j; reduce over k (rows); store h bf16
    #pragma unroll
    for (int g = 0; g < 2; g++) {
        // hoist the 12 row pointers for this group (rows mt*16+quad*4+r)
        const float* pv[12];
        #pragma unroll
        for (int mm = 0; mm < 3; mm++)
            #pragma unroll
            for (int r = 0; r < 4; r++)
                pv[mm * 4 + r] = h_V + rowoff_s[(g * 3 + mm) * 16 + quad * 4 + r] + wn0 + l16;

        #pragma unroll
        for (int nt = 0; nt < 6; nt++) {
            float s = 0.f;
            #pragma unroll
            for (int mm = 0; mm < 3; mm++) {
                #pragma unroll
                for (int r = 0; r < 4; r++) {
                    float w = gelu_fast(acc[g * 3 + mm][nt][r] + b2v[nt]);
                    s = fmaf(w, pv[mm * 4 + r][nt * 16], s);
                }
            }
            s += __shfl_xor(s, 16, 64);
            s += __shfl_xor(s, 32, 64);
            if (lane < 16)
                hbufB[(size_t)(bl0 + g) * ND + wn0 + nt * 16 + lane] = f2bf(s);
        }
    }
}

// ---------------------------------------------------------------------------
// Kernel 2: MLP head via MFMA. One wave (64 thr) per 16 rows.
// layer1: [16x384]@[384x128] bf16 MFMA; gelu -> T1 (LDS, stride 136);
// layer2: [16x128]@[128x64]; gelu; layer3: 64-dot via VALU + shuffles;
// masked per-batch sum -> one atomic per block.
// ---------------------------------------------------------------------------
__global__ __launch_bounds__(64) void head_kernel(
    const unsigned short* __restrict__ hbufB,
    const unsigned short* __restrict__ hw1p, const float* __restrict__ hb1,
    const unsigned short* __restrict__ hw2p, const float* __restrict__ hb2,
    const float* __restrict__ hw3, const float* __restrict__ hb3,
    const float* __restrict__ mask, float* __restrict__ dGsum)
{
    __shared__ unsigned short T1[16 * 136];
    const int lane = threadIdx.x;
    const int quad = lane >> 4, l16 = lane & 15;
    const int row0 = blockIdx.x * 16;

    // ---- layer1: K=384, N=128 ----
    f32x4 acc1[8];
    #pragma unroll
    for (int nt = 0; nt < 8; nt++) acc1[nt] = (f32x4){0.f, 0.f, 0.f, 0.f};

    for (int kt = 0; kt < 12; kt++) {
        short8 a = *(const short8*)(hbufB + (size_t)(row0 + l16) * ND + kt * 32 + quad * 8);
        #pragma unroll
        for (int nt = 0; nt < 8; nt++) {
            short8 b = *(const short8*)(hw1p + (size_t)((kt * 8 + nt) * 64 + lane) * 8);
            acc1[nt] = __builtin_amdgcn_mfma_f32_16x16x32_bf16(a, b, acc1[nt], 0, 0, 0);
        }
    }

    // gelu + bias -> T1 bf16
    #pragma unroll
    for (int nt = 0; nt < 8; nt++) {
        int col = nt * 16 + l16;
        float b1 = hb1[col];
        #pragma unroll
        for (int r = 0; r < 4; r++)
            T1[(quad * 4 + r) * 136 + col] = f2bf_rhu(gelu_fast(acc1[nt][r] + b1));
    }
    __syncthreads();

    // ---- layer2: K=128, N=64 ----
    f32x4 acc2[4];
    #pragma unroll
    for (int nt = 0; nt < 4; nt++) acc2[nt] = (f32x4){0.f, 0.f, 0.f, 0.f};

    #pragma unroll
    for (int kt = 0; kt < 4; kt++) {
        short8 a = *(const short8*)&T1[l16 * 136 + kt * 32 + quad * 8];
        #pragma unroll
        for (int nt = 0; nt < 4; nt++) {
            short8 b = *(const short8*)(hw2p + (size_t)((kt * 4 + nt) * 64 + lane) * 8);
            acc2[nt] = __builtin_amdgcn_mfma_f32_16x16x32_bf16(a, b, acc2[nt], 0, 0, 0);
        }
    }

    // ---- layer3: gelu then 64-dot + masked accumulation ----
    float w3[4], b2[4];
    #pragma unroll
    for (int nt = 0; nt < 4; nt++) { w3[nt] = hw3[nt * 16 + l16]; b2[nt] = hb2[nt * 16 + l16]; }

    float dsum = 0.f;
    const float hb3v = hb3[0];
    #pragma unroll
    for (int r = 0; r < 4; r++) {
        float pr = 0.f;
        #pragma unroll
        for (int nt = 0; nt < 4; nt++)
            pr = fmaf(gelu_fast(acc2[nt][r] + b2[nt]), w3[nt], pr);
        pr += __shfl_xor(pr, 1, 64);
        pr += __shfl_xor(pr, 2, 64);
        pr += __shfl_xor(pr, 4, 64);
        pr += __shfl_xor(pr, 8, 64);
        if (l16 == 0) {
            int grow = row0 + quad * 4 + r;
            dsum = fmaf(pr + hb3v, mask[grow], dsum);
        }
    }
    dsum += __shfl_xor(dsum, 16, 64);
    dsum += __shfl_xor(dsum, 32, 64);
    if (lane == 0) atomicAdd(&dGsum[row0 >> 9], dsum);
}

// ---------------------------------------------------------------------------
// Kernel 3: out[b] = dGsum[b] / sqrt(clip(sum(mask[b,:]), 1))
// ---------------------------------------------------------------------------
__global__ void finalize_kernel(const float* __restrict__ dGsum,
                                const float* __restrict__ mask,
                                float* __restrict__ out) {
    int t = threadIdx.x;
    int b = t >> 4, j = t & 15;
    float ms = 0.f;
    for (int l = j; l < NL; l += 16) ms += mask[b * NL + l];
    ms += __shfl_xor(ms, 1, 64);
    ms += __shfl_xor(ms, 2, 64);
    ms += __shfl_xor(ms, 4, 64);
    ms += __shfl_xor(ms, 8, 64);
    if (j == 0) {
        ms = fmaxf(ms, 1.0f);
        out[b] = dGsum[b] / sqrtf(ms);
    }
}

extern "C" void kernel_launch(void* const* d_in, const int* in_sizes, int n_in,
                              void* d_out, int out_size, void* d_ws, size_t ws_size,
                              hipStream_t stream) {
    const float* h_V  = (const float*)d_in[0];
    const float* h_E  = (const float*)d_in[1];
    const float* mask = (const float*)d_in[2];
    const float* fw1  = (const float*)d_in[3];
    const float* fb1  = (const float*)d_in[4];
    const float* fw2  = (const float*)d_in[5];
    const float* fb2  = (const float*)d_in[6];
    const float* hw1  = (const float*)d_in[7];
    const float* hb1  = (const float*)d_in[8];
    const float* hw2  = (const float*)d_in[9];
    const float* hb2  = (const float*)d_in[10];
    const float* hw3  = (const float*)d_in[11];
    const float* hb3  = (const float*)d_in[12];
    const int*   E_idx = (const int*)d_in[13];
    float* out = (float*)d_out;

    char* ws = (char*)d_ws;
    unsigned short* fw1p = (unsigned short*)ws;              // 128*384*2 =  98304 B
    unsigned short* fw2p = (unsigned short*)(ws + 98304);    // 384*384*2 = 294912 B
    unsigned short* hw1p = (unsigned short*)(ws + 393216);   // 384*128*2 =  98304 B
    unsigned short* hw2p = (unsigned short*)(ws + 491520);   // 128*64*2  =  16384 B
    float* dGsum = (float*)(ws + 507904);                    // 64 B
    unsigned short* hbufB = (unsigned short*)(ws + 512000);  // 8192*384*2 = 6.3 MB

    pack_weights<<<992, 256, 0, stream>>>(fw1, fw2, hw1, hw2, fw1p, fw2p, hw1p, hw2p, dGsum);
    cfconv_kernel<<<(NB * NL) / 2, 256, 0, stream>>>(h_V, h_E, fb1, fb2, fw1p, fw2p, E_idx, hbufB);
    head_kernel<<<(NB * NL) / 16, 64, 0, stream>>>(hbufB, hw1p, hb1, hw2p, hb2, hw3, hb3, mask, dGsum);
    finalize_kernel<<<1, 256, 0, stream>>>(dGsum, mask, out);
}

// Round 4
// 465.361 us; speedup vs baseline: 1.8562x; 1.0771x over previous
//
#include <hip/hip_runtime.h>
#include <hip/hip_bf16.h>
#include <math.h>

// B=16 L=512 K=48 E=128 D=384 H=128
#define NB 16
#define NL 512
#define NK 48
#define NE 128
#define ND 384
#define NH 128

typedef __attribute__((ext_vector_type(8))) short short8;
typedef __attribute__((ext_vector_type(4))) float f32x4;

// fast erf-gelu: tanh-form reduced to sigmoid, sigmoid via hw exp2 + rcp.
__device__ __forceinline__ float gelu_fast(float x) {
    float t = x * fmaf(x * x, -0.1029437f, -2.3022087f);
    float e = __builtin_amdgcn_exp2f(t);
    return x * __builtin_amdgcn_rcpf(1.0f + e);
}

// round-to-nearest-even f32 -> bf16 bits (used in pack, once per launch)
__device__ __forceinline__ unsigned short f2bf(float x) {
    union { float f; unsigned u; } v; v.f = x;
    unsigned r = v.u + 0x7fffu + ((v.u >> 16) & 1u);
    return (unsigned short)(r >> 16);
}

// cheap round-half-up f32 -> bf16 bits (2 inst)
__device__ __forceinline__ unsigned short f2bf_rhu(float x) {
    union { float f; unsigned u; } v; v.f = x;
    return (unsigned short)((v.u + 0x8000u) >> 16);
}

// pack two f32 -> (bf16(a)<<16)|bf16(b), round-half-up: 2 adds + 1 v_perm
__device__ __forceinline__ unsigned pk_bf16(float a, float b) {
    union { float f; unsigned u; } ua, ub; ua.f = a; ub.f = b;
    return __builtin_amdgcn_perm(ua.u + 0x8000u, ub.u + 0x8000u, 0x07060302u);
}

// ---------------------------------------------------------------------------
// Kernel 0: pack fw1/fw2/hw1/hw2 into bf16 MFMA-B-fragment order:
// dst[((kt*NT+nt)*64 + quad*16 + nc)*8 + j], kt=k>>5, quad=(k>>3)&3, j=k&7,
// nt=n>>4, nc=n&15.  Also zero the per-batch dG accumulator.
// ---------------------------------------------------------------------------
__global__ void pack_weights(const float* __restrict__ fw1,
                             const float* __restrict__ fw2,
                             const float* __restrict__ hw1,
                             const float* __restrict__ hw2,
                             unsigned short* __restrict__ fw1p,
                             unsigned short* __restrict__ fw2p,
                             unsigned short* __restrict__ hw1p,
                             unsigned short* __restrict__ hw2p,
                             float* __restrict__ dGsum) {
    int tid = blockIdx.x * 256 + threadIdx.x;
    if (tid < NB) dGsum[tid] = 0.0f;
    if (tid < NE * ND) {                                  // fw1 128x384
        int k = tid / ND, n = tid % ND;
        int dst = (((k >> 5) * 24 + (n >> 4)) * 64 + ((k >> 3) & 3) * 16 + (n & 15)) * 8 + (k & 7);
        fw1p[dst] = f2bf(fw1[tid]);
    } else if (tid < NE * ND + ND * ND) {                 // fw2 384x384
        int i = tid - NE * ND;
        int k = i / ND, n = i % ND;
        int dst = (((k >> 5) * 24 + (n >> 4)) * 64 + ((k >> 3) & 3) * 16 + (n & 15)) * 8 + (k & 7);
        fw2p[dst] = f2bf(fw2[i]);
    } else if (tid < NE * ND + ND * ND + ND * NH) {       // hw1 384x128
        int i = tid - (NE * ND + ND * ND);
        int k = i / NH, n = i % NH;
        int dst = (((k >> 5) * 8 + (n >> 4)) * 64 + ((k >> 3) & 3) * 16 + (n & 15)) * 8 + (k & 7);
        hw1p[dst] = f2bf(hw1[i]);
    } else if (tid < NE * ND + ND * ND + ND * NH + NH * (NH / 2)) {  // hw2 128x64
        int i = tid - (NE * ND + ND * ND + ND * NH);
        int k = i / (NH / 2), n = i % (NH / 2);
        int dst = (((k >> 5) * 4 + (n >> 4)) * 64 + ((k >> 3) & 3) * 16 + (n & 15)) * 8 + (k & 7);
        hw2p[dst] = f2bf(hw2[i]);
    }
}

// ---------------------------------------------------------------------------
// Kernel 1: fused CFConv.  One block = 2 (b,l) groups = 96 edge-rows.
// GEMM1 [96x128]@[128x384] -> gelu -> bf16 T (LDS) -> GEMM2 [96x384]@[384x384]
// (GEMM2 software-pipelined: B-fragments for kt+1 prefetched during kt MFMAs)
// epilogue: bias+gelu -> W, gather x_j = h_V[E_idx], reduce over k -> h[b,l,:]
// output h written as bf16 row-major (A-fragment-ready for head_kernel).
// ---------------------------------------------------------------------------
__global__ __launch_bounds__(256, 2) void cfconv_kernel(
    const float* __restrict__ h_V, const float* __restrict__ h_E,
    const float* __restrict__ fb1, const float* __restrict__ fb2,
    const unsigned short* __restrict__ fw1p,
    const unsigned short* __restrict__ fw2p,
    const int* __restrict__ E_idx, unsigned short* __restrict__ hbufB)
{
    __shared__ unsigned short smem[96 * 392];  // T (stride 392); head aliased as Ea (stride 136)
    __shared__ int rowoff_s[96];

    const int t = threadIdx.x;
    const int wave = t >> 6, lane = t & 63;
    const int quad = lane >> 4, l16 = lane & 15;
    const int bl0 = blockIdx.x * 2;
    const int wn0 = wave * 96;   // this wave's column base (384 / 4 waves)

    // E_idx -> precomputed h_V row offsets
    if (t < 96) {
        int g = t / 48, k = t - g * 48;
        int bl = bl0 + g;
        int idx = E_idx[bl * NK + k];
        rowoff_s[t] = ((bl >> 9) * NL + idx) * ND;
    }

    // stage h_E (2 groups, 96x128 f32) -> bf16 LDS rows (stride 136)
    {
        const float4* src = (const float4*)(h_E + (size_t)bl0 * (NK * NE));
        #pragma unroll
        for (int i = 0; i < 12; i++) {
            int v = i * 256 + t;         // 3072 float4
            float4 d = src[v];
            int r = v >> 5;              // 32 float4 per 128-col row
            int c = (v & 31) * 4;
            uint2 u;
            u.x = pk_bf16(d.y, d.x);
            u.y = pk_bf16(d.w, d.z);
            *(uint2*)&smem[r * 136 + c] = u;
        }
    }
    __syncthreads();

    f32x4 acc[6][6];

    // ---- GEMM1: K = 128 (4 k-steps, fully unrolled) ----
    #pragma unroll
    for (int mt = 0; mt < 6; mt++)
        #pragma unroll
        for (int nt = 0; nt < 6; nt++)
            acc[mt][nt] = (f32x4){0.f, 0.f, 0.f, 0.f};

    #pragma unroll
    for (int kt = 0; kt < 4; kt++) {
        short8 bfrag[6], afrag[6];
        #pragma unroll
        for (int nt = 0; nt < 6; nt++)
            bfrag[nt] = *(const short8*)(fw1p + (size_t)((kt * 24 + (wn0 >> 4) + nt) * 64 + lane) * 8);
        #pragma unroll
        for (int mt = 0; mt < 6; mt++)
            afrag[mt] = *(const short8*)&smem[(mt * 16 + l16) * 136 + kt * 32 + quad * 8];
        #pragma unroll
        for (int mt = 0; mt < 6; mt++)
            #pragma unroll
            for (int nt = 0; nt < 6; nt++)
                acc[mt][nt] = __builtin_amdgcn_mfma_f32_16x16x32_bf16(
                    afrag[mt], bfrag[nt], acc[mt][nt], 0, 0, 0);
    }
    __syncthreads();  // all waves done reading Ea; smem becomes T

    // epilogue1: +fb1, gelu, -> bf16 T (stride 392)
    #pragma unroll
    for (int nt = 0; nt < 6; nt++) {
        int col = wn0 + nt * 16 + l16;
        float b1 = fb1[col];
        #pragma unroll
        for (int mt = 0; mt < 6; mt++) {
            int rowb = mt * 16 + quad * 4;
            #pragma unroll
            for (int r = 0; r < 4; r++)
                smem[(rowb + r) * 392 + col] = f2bf_rhu(gelu_fast(acc[mt][nt][r] + b1));
        }
    }
    __syncthreads();

    // ---- GEMM2: K = 384 (12 k-steps), double-buffered B prefetch ----
    #pragma unroll
    for (int mt = 0; mt < 6; mt++)
        #pragma unroll
        for (int nt = 0; nt < 6; nt++)
            acc[mt][nt] = (f32x4){0.f, 0.f, 0.f, 0.f};

    {
        short8 b0[6], b1[6], af[6];
        #define LOADB(kt, bf)                                                            \
            _Pragma("unroll")                                                            \
            for (int nt = 0; nt < 6; nt++)                                               \
                bf[nt] = *(const short8*)(fw2p +                                         \
                    (size_t)(((kt) * 24 + (wn0 >> 4) + nt) * 64 + lane) * 8);
        #define LOADA(kt)                                                                \
            _Pragma("unroll")                                                            \
            for (int mt = 0; mt < 6; mt++)                                               \
                af[mt] = *(const short8*)&smem[(mt * 16 + l16) * 392 + (kt) * 32 + quad * 8];
        #define MFMAS(bf)                                                                \
            _Pragma("unroll")                                                            \
            for (int mt = 0; mt < 6; mt++)                                               \
                _Pragma("unroll")                                                        \
                for (int nt = 0; nt < 6; nt++)                                           \
                    acc[mt][nt] = __builtin_amdgcn_mfma_f32_16x16x32_bf16(               \
                        af[mt], bf[nt], acc[mt][nt], 0, 0, 0);

        LOADB(0, b0);
        for (int kt = 0; kt < 10; kt += 2) {
            LOADB(kt + 1, b1);
            LOADA(kt);
            MFMAS(b0);
            LOADB(kt + 2, b0);
            LOADA(kt + 1);
            MFMAS(b1);
        }
        // tail: kt = 10, 11 (b0 holds kt=10)
        LOADB(11, b1);
        LOADA(10);
        MFMAS(b0);
        LOADA(11);
        MFMAS(b1);
        #undef LOADB
        #undef LOADA
        #undef MFMAS
    }

    // hoist biases
    float b2v[6];
    #pragma unroll
    for (int nt = 0; nt < 6; nt++) b2v[nt] = fb2[wn0 + nt * 16 + l16];

    // epilogue2: +fb2, gelu -> W; gather x_j; reduce over k (rows); store h bf16.
    // Per mm: build 4 row pointers, batch-issue 24 gather loads (immediate col
    // offsets), then run the dependent gelu/fma chain.
    #pragma unroll
    for (int g = 0; g < 2; g++) {
        float s[6] = {0.f, 0.f, 0.f, 0.f, 0.f, 0.f};
        #pragma unroll
        for (int mm = 0; mm < 3; mm++) {
            const int rb = (g * 3 + mm) * 16 + quad * 4;
            const float* p0 = h_V + rowoff_s[rb + 0] + wn0 + l16;
            const float* p1 = h_V + rowoff_s[rb + 1] + wn0 + l16;
            const float* p2 = h_V + rowoff_s[rb + 2] + wn0 + l16;
            const float* p3 = h_V + rowoff_s[rb + 3] + wn0 + l16;
            float xv[6][4];
            #pragma unroll
            for (int nt = 0; nt < 6; nt++) {
                xv[nt][0] = p0[nt * 16];
                xv[nt][1] = p1[nt * 16];
                xv[nt][2] = p2[nt * 16];
                xv[nt][3] = p3[nt * 16];
            }
            #pragma unroll
            for (int nt = 0; nt < 6; nt++)
                #pragma unroll
                for (int r = 0; r < 4; r++)
                    s[nt] = fmaf(gelu_fast(acc[g * 3 + mm][nt][r] + b2v[nt]), xv[nt][r], s[nt]);
        }
        #pragma unroll
        for (int nt = 0; nt < 6; nt++) {
            float v = s[nt];
            v += __shfl_xor(v, 16, 64);
            v += __shfl_xor(v, 32, 64);
            if (lane < 16)
                hbufB[(size_t)(bl0 + g) * ND + wn0 + nt * 16 + lane] = f2bf(v);
        }
    }
}

// ---------------------------------------------------------------------------
// Kernel 2: MLP head via MFMA. One wave (64 thr) per 16 rows.
// layer1: [16x384]@[384x128] bf16 MFMA; gelu -> T1 (LDS, stride 136);
// layer2: [16x128]@[128x64]; gelu; layer3: 64-dot via VALU + shuffles;
// masked per-batch sum -> one atomic per block.
// ---------------------------------------------------------------------------
__global__ __launch_bounds__(64) void head_kernel(
    const unsigned short* __restrict__ hbufB,
    const unsigned short* __restrict__ hw1p, const float* __restrict__ hb1,
    const unsigned short* __restrict__ hw2p, const float* __restrict__ hb2,
    const float* __restrict__ hw3, const float* __restrict__ hb3,
    const float* __restrict__ mask, float* __restrict__ dGsum)
{
    __shared__ unsigned short T1[16 * 136];
    const int lane = threadIdx.x;
    const int quad = lane >> 4, l16 = lane & 15;
    const int row0 = blockIdx.x * 16;

    // ---- layer1: K=384, N=128 ----
    f32x4 acc1[8];
    #pragma unroll
    for (int nt = 0; nt < 8; nt++) acc1[nt] = (f32x4){0.f, 0.f, 0.f, 0.f};

    for (int kt = 0; kt < 12; kt++) {
        short8 a = *(const short8*)(hbufB + (size_t)(row0 + l16) * ND + kt * 32 + quad * 8);
        #pragma unroll
        for (int nt = 0; nt < 8; nt++) {
            short8 b = *(const short8*)(hw1p + (size_t)((kt * 8 + nt) * 64 + lane) * 8);
            acc1[nt] = __builtin_amdgcn_mfma_f32_16x16x32_bf16(a, b, acc1[nt], 0, 0, 0);
        }
    }

    // gelu + bias -> T1 bf16
    #pragma unroll
    for (int nt = 0; nt < 8; nt++) {
        int col = nt * 16 + l16;
        float b1 = hb1[col];
        #pragma unroll
        for (int r = 0; r < 4; r++)
            T1[(quad * 4 + r) * 136 + col] = f2bf_rhu(gelu_fast(acc1[nt][r] + b1));
    }
    __syncthreads();

    // ---- layer2: K=128, N=64 ----
    f32x4 acc2[4];
    #pragma unroll
    for (int nt = 0; nt < 4; nt++) acc2[nt] = (f32x4){0.f, 0.f, 0.f, 0.f};

    #pragma unroll
    for (int kt = 0; kt < 4; kt++) {
        short8 a = *(const short8*)&T1[l16 * 136 + kt * 32 + quad * 8];
        #pragma unroll
        for (int nt = 0; nt < 4; nt++) {
            short8 b = *(const short8*)(hw2p + (size_t)((kt * 4 + nt) * 64 + lane) * 8);
            acc2[nt] = __builtin_amdgcn_mfma_f32_16x16x32_bf16(a, b, acc2[nt], 0, 0, 0);
        }
    }

    // ---- layer3: gelu then 64-dot + masked accumulation ----
    float w3[4], b2[4];
    #pragma unroll
    for (int nt = 0; nt < 4; nt++) { w3[nt] = hw3[nt * 16 + l16]; b2[nt] = hb2[nt * 16 + l16]; }

    float dsum = 0.f;
    const float hb3v = hb3[0];
    #pragma unroll
    for (int r = 0; r < 4; r++) {
        float pr = 0.f;
        #pragma unroll
        for (int nt = 0; nt < 4; nt++)
            pr = fmaf(gelu_fast(acc2[nt][r] + b2[nt]), w3[nt], pr);
        pr += __shfl_xor(pr, 1, 64);
        pr += __shfl_xor(pr, 2, 64);
        pr += __shfl_xor(pr, 4, 64);
        pr += __shfl_xor(pr, 8, 64);
        if (l16 == 0) {
            int grow = row0 + quad * 4 + r;
            dsum = fmaf(pr + hb3v, mask[grow], dsum);
        }
    }
    dsum += __shfl_xor(dsum, 16, 64);
    dsum += __shfl_xor(dsum, 32, 64);
    if (lane == 0) atomicAdd(&dGsum[row0 >> 9], dsum);
}

// ---------------------------------------------------------------------------
// Kernel 3: out[b] = dGsum[b] / sqrt(clip(sum(mask[b,:]), 1))
// ---------------------------------------------------------------------------
__global__ void finalize_kernel(const float* __restrict__ dGsum,
                                const float* __restrict__ mask,
                                float* __restrict__ out) {
    int t = threadIdx.x;
    int b = t >> 4, j = t & 15;
    float ms = 0.f;
    for (int l = j; l < NL; l += 16) ms += mask[b * NL + l];
    ms += __shfl_xor(ms, 1, 64);
    ms += __shfl_xor(ms, 2, 64);
    ms += __shfl_xor(ms, 4, 64);
    ms += __shfl_xor(ms, 8, 64);
    if (j == 0) {
        ms = fmaxf(ms, 1.0f);
        out[b] = dGsum[b] / sqrtf(ms);
    }
}

extern "C" void kernel_launch(void* const* d_in, const int* in_sizes, int n_in,
                              void* d_out, int out_size, void* d_ws, size_t ws_size,
                              hipStream_t stream) {
    const float* h_V  = (const float*)d_in[0];
    const float* h_E  = (const float*)d_in[1];
    const float* mask = (const float*)d_in[2];
    const float* fw1  = (const float*)d_in[3];
    const float* fb1  = (const float*)d_in[4];
    const float* fw2  = (const float*)d_in[5];
    const float* fb2  = (const float*)d_in[6];
    const float* hw1  = (const float*)d_in[7];
    const float* hb1  = (const float*)d_in[8];
    const float* hw2  = (const float*)d_in[9];
    const float* hb2  = (const float*)d_in[10];
    const float* hw3  = (const float*)d_in[11];
    const float* hb3  = (const float*)d_in[12];
    const int*   E_idx = (const int*)d_in[13];
    float* out = (float*)d_out;

    char* ws = (char*)d_ws;
    unsigned short* fw1p = (unsigned short*)ws;              // 128*384*2 =  98304 B
    unsigned short* fw2p = (unsigned short*)(ws + 98304);    // 384*384*2 = 294912 B
    unsigned short* hw1p = (unsigned short*)(ws + 393216);   // 384*128*2 =  98304 B
    unsigned short* hw2p = (unsigned short*)(ws + 491520);   // 128*64*2  =  16384 B
    float* dGsum = (float*)(ws + 507904);                    // 64 B
    unsigned short* hbufB = (unsigned short*)(ws + 512000);  // 8192*384*2 = 6.3 MB

    pack_weights<<<992, 256, 0, stream>>>(fw1, fw2, hw1, hw2, fw1p, fw2p, hw1p, hw2p, dGsum);
    cfconv_kernel<<<(NB * NL) / 2, 256, 0, stream>>>(h_V, h_E, fb1, fb2, fw1p, fw2p, E_idx, hbufB);
    head_kernel<<<(NB * NL) / 16, 64, 0, stream>>>(hbufB, hw1p, hb1, hw2p, hb2, hw3, hb3, mask, dGsum);
    finalize_kernel<<<1, 256, 0, stream>>>(dGsum, mask, out);
}

// Round 5
// 453.775 us; speedup vs baseline: 1.9035x; 1.0255x over previous
//
#include <hip/hip_runtime.h>
#include <hip/hip_bf16.h>
#include <math.h>

// B=16 L=512 K=48 E=128 D=384 H=128
#define NB 16
#define NL 512
#define NK 48
#define NE 128
#define ND 384
#define NH 128

typedef __attribute__((ext_vector_type(8))) short short8;
typedef __attribute__((ext_vector_type(4))) float f32x4;

// fast erf-gelu: tanh-form reduced to sigmoid, sigmoid via hw exp2 + rcp.
__device__ __forceinline__ float gelu_fast(float x) {
    float t = x * fmaf(x * x, -0.1029437f, -2.3022087f);
    float e = __builtin_amdgcn_exp2f(t);
    return x * __builtin_amdgcn_rcpf(1.0f + e);
}

// round-to-nearest-even f32 -> bf16 bits (used in pack, once per launch)
__device__ __forceinline__ unsigned short f2bf(float x) {
    union { float f; unsigned u; } v; v.f = x;
    unsigned r = v.u + 0x7fffu + ((v.u >> 16) & 1u);
    return (unsigned short)(r >> 16);
}

// cheap round-half-up f32 -> bf16 bits (2 inst)
__device__ __forceinline__ unsigned short f2bf_rhu(float x) {
    union { float f; unsigned u; } v; v.f = x;
    return (unsigned short)((v.u + 0x8000u) >> 16);
}

// pack two f32 -> (bf16(a)<<16)|bf16(b), round-half-up: 2 adds + 1 v_perm
__device__ __forceinline__ unsigned pk_bf16(float a, float b) {
    union { float f; unsigned u; } ua, ub; ua.f = a; ub.f = b;
    return __builtin_amdgcn_perm(ua.u + 0x8000u, ub.u + 0x8000u, 0x07060302u);
}

// ---------------------------------------------------------------------------
// Kernel 0: pack fw1/fw2/hw1/hw2 into bf16 MFMA fragment order:
// dst[((kt*NT+nt)*64 + quad*16 + nc)*8 + j], kt=k>>5, quad=(k>>3)&3, j=k&7,
// nt=n>>4, nc=n&15.  (Same buffer serves as B[k][n] frags, or as A-frags of
// the transpose W^T[n][k] — lane&15 maps to n either way.)
// ---------------------------------------------------------------------------
__global__ void pack_weights(const float* __restrict__ fw1,
                             const float* __restrict__ fw2,
                             const float* __restrict__ hw1,
                             const float* __restrict__ hw2,
                             unsigned short* __restrict__ fw1p,
                             unsigned short* __restrict__ fw2p,
                             unsigned short* __restrict__ hw1p,
                             unsigned short* __restrict__ hw2p) {
    int tid = blockIdx.x * 256 + threadIdx.x;
    if (tid < NE * ND) {                                  // fw1 128x384
        int k = tid / ND, n = tid % ND;
        int dst = (((k >> 5) * 24 + (n >> 4)) * 64 + ((k >> 3) & 3) * 16 + (n & 15)) * 8 + (k & 7);
        fw1p[dst] = f2bf(fw1[tid]);
    } else if (tid < NE * ND + ND * ND) {                 // fw2 384x384
        int i = tid - NE * ND;
        int k = i / ND, n = i % ND;
        int dst = (((k >> 5) * 24 + (n >> 4)) * 64 + ((k >> 3) & 3) * 16 + (n & 15)) * 8 + (k & 7);
        fw2p[dst] = f2bf(fw2[i]);
    } else if (tid < NE * ND + ND * ND + ND * NH) {       // hw1 384x128
        int i = tid - (NE * ND + ND * ND);
        int k = i / NH, n = i % NH;
        int dst = (((k >> 5) * 8 + (n >> 4)) * 64 + ((k >> 3) & 3) * 16 + (n & 15)) * 8 + (k & 7);
        hw1p[dst] = f2bf(hw1[i]);
    } else if (tid < NE * ND + ND * ND + ND * NH + NH * (NH / 2)) {  // hw2 128x64
        int i = tid - (NE * ND + ND * ND + ND * NH);
        int k = i / (NH / 2), n = i % (NH / 2);
        int dst = (((k >> 5) * 4 + (n >> 4)) * 64 + ((k >> 3) & 3) * 16 + (n & 15)) * 8 + (k & 7);
        hw2p[dst] = f2bf(hw2[i]);
    }
}

// ---------------------------------------------------------------------------
// Kernel 1: fused CFConv.  One block = 1 (b,l) group = 48 edge-rows.
// GEMM1 (transposed: D^T = fw1^T @ h_E^T) [384x128]@[128x48] -> gelu ->
// bf16 T via ds_write_b64 -> GEMM2 [48x384]@[384x384] (dbuf B prefetch) ->
// epilogue: bias+gelu -> W, gather x_j = h_V[E_idx], reduce over k.
// LDS ~51KB -> 3 blocks/CU.
// ---------------------------------------------------------------------------
__global__ __launch_bounds__(256, 3) void cfconv_kernel(
    const float* __restrict__ h_V, const float* __restrict__ h_E,
    const float* __restrict__ fb1, const float* __restrict__ fb2,
    const unsigned short* __restrict__ fw1p,
    const unsigned short* __restrict__ fw2p,
    const int* __restrict__ E_idx, unsigned short* __restrict__ hbufB)
{
    __shared__ unsigned short Ea[48 * 136];   // h_E tile, bf16, stride 136
    __shared__ unsigned short T[48 * 392];    // gelu(GEMM1) tile, stride 392
    __shared__ int rowoff_s[48];

    const int t = threadIdx.x;
    const int wave = t >> 6, lane = t & 63;
    const int quad = lane >> 4, l16 = lane & 15;
    const int bl = blockIdx.x;
    const int wn0 = wave * 96;   // this wave's column slice of 384

    if (t < 48)
        rowoff_s[t] = ((bl >> 9) * NL + E_idx[bl * NK + t]) * ND;

    // stage h_E (48x128 f32) -> bf16 Ea
    {
        const float4* src = (const float4*)(h_E + (size_t)bl * (NK * NE));
        #pragma unroll
        for (int i = 0; i < 6; i++) {
            int v = i * 256 + t;         // 1536 float4
            float4 d = src[v];
            int r = v >> 5;              // 32 float4 per 128-col row
            int c = (v & 31) * 4;
            uint2 u;
            u.x = pk_bf16(d.y, d.x);
            u.y = pk_bf16(d.w, d.z);
            *(uint2*)&Ea[r * 136 + c] = u;
        }
    }
    __syncthreads();

    f32x4 acc[18];

    // ---- GEMM1 (transposed): M=n (wave slice 96, 6 mt), N=edge (48, 3 nt),
    //      K=128 (4 kt).  A = fw1^T from fw1p; B = h_E^T from Ea.
    #pragma unroll
    for (int i = 0; i < 18; i++) acc[i] = (f32x4){0.f, 0.f, 0.f, 0.f};

    #pragma unroll
    for (int kt = 0; kt < 4; kt++) {
        short8 aw[6], be[3];
        #pragma unroll
        for (int mt = 0; mt < 6; mt++)
            aw[mt] = *(const short8*)(fw1p + (size_t)((kt * 24 + (wn0 >> 4) + mt) * 64 + lane) * 8);
        #pragma unroll
        for (int nt = 0; nt < 3; nt++)
            be[nt] = *(const short8*)&Ea[(nt * 16 + l16) * 136 + kt * 32 + quad * 8];
        #pragma unroll
        for (int mt = 0; mt < 6; mt++)
            #pragma unroll
            for (int nt = 0; nt < 3; nt++)
                acc[mt * 3 + nt] = __builtin_amdgcn_mfma_f32_16x16x32_bf16(
                    aw[mt], be[nt], acc[mt * 3 + nt], 0, 0, 0);
    }

    // epilogue1: +fb1, gelu -> T.  C/D of transposed GEMM1: col=edge (l16),
    // row = n-within-tile (quad*4+r): 4 consecutive n per lane -> b64 writes.
    #pragma unroll
    for (int mt = 0; mt < 6; mt++) {
        float4 b1v = *(const float4*)&fb1[wn0 + mt * 16 + quad * 4];
        #pragma unroll
        for (int nt = 0; nt < 3; nt++) {
            f32x4 a = acc[mt * 3 + nt];
            float v0 = gelu_fast(a[0] + b1v.x);
            float v1 = gelu_fast(a[1] + b1v.y);
            float v2 = gelu_fast(a[2] + b1v.z);
            float v3 = gelu_fast(a[3] + b1v.w);
            uint2 u;
            u.x = pk_bf16(v1, v0);
            u.y = pk_bf16(v3, v2);
            *(uint2*)&T[(nt * 16 + l16) * 392 + wn0 + mt * 16 + quad * 4] = u;
        }
    }
    __syncthreads();

    // ---- GEMM2: M=edge (48, 3 mt), N=wave slice 96 (6 nt), K=384 (12 kt),
    //      double-buffered B prefetch.
    #pragma unroll
    for (int i = 0; i < 18; i++) acc[i] = (f32x4){0.f, 0.f, 0.f, 0.f};

    {
        short8 b0[6], b1[6], af[3];
        #define LOADB(kt, bf)                                                            \
            _Pragma("unroll")                                                            \
            for (int nt = 0; nt < 6; nt++)                                               \
                bf[nt] = *(const short8*)(fw2p +                                         \
                    (size_t)(((kt) * 24 + (wn0 >> 4) + nt) * 64 + lane) * 8);
        #define LOADA(kt)                                                                \
            _Pragma("unroll")                                                            \
            for (int mt = 0; mt < 3; mt++)                                               \
                af[mt] = *(const short8*)&T[(mt * 16 + l16) * 392 + (kt) * 32 + quad * 8];
        #define MFMAS(bf)                                                                \
            _Pragma("unroll")                                                            \
            for (int mt = 0; mt < 3; mt++)                                               \
                _Pragma("unroll")                                                        \
                for (int nt = 0; nt < 6; nt++)                                           \
                    acc[nt * 3 + mt] = __builtin_amdgcn_mfma_f32_16x16x32_bf16(          \
                        af[mt], bf[nt], acc[nt * 3 + mt], 0, 0, 0);

        LOADB(0, b0);
        for (int kt = 0; kt < 10; kt += 2) {
            LOADB(kt + 1, b1);
            LOADA(kt);
            MFMAS(b0);
            LOADB(kt + 2, b0);
            LOADA(kt + 1);
            MFMAS(b1);
        }
        LOADB(11, b1);
        LOADA(10);
        MFMAS(b0);
        LOADA(11);
        MFMAS(b1);
        #undef LOADB
        #undef LOADA
        #undef MFMAS
    }

    // epilogue2: +fb2, gelu -> W; gather x_j; reduce over all 48 rows; store.
    float b2v[6];
    #pragma unroll
    for (int nt = 0; nt < 6; nt++) b2v[nt] = fb2[wn0 + nt * 16 + l16];

    float s[6] = {0.f, 0.f, 0.f, 0.f, 0.f, 0.f};
    #pragma unroll
    for (int mt = 0; mt < 3; mt++) {
        const int rb = mt * 16 + quad * 4;
        const float* p0 = h_V + rowoff_s[rb + 0] + wn0 + l16;
        const float* p1 = h_V + rowoff_s[rb + 1] + wn0 + l16;
        const float* p2 = h_V + rowoff_s[rb + 2] + wn0 + l16;
        const float* p3 = h_V + rowoff_s[rb + 3] + wn0 + l16;
        float xv[6][4];
        #pragma unroll
        for (int nt = 0; nt < 6; nt++) {
            xv[nt][0] = p0[nt * 16];
            xv[nt][1] = p1[nt * 16];
            xv[nt][2] = p2[nt * 16];
            xv[nt][3] = p3[nt * 16];
        }
        #pragma unroll
        for (int nt = 0; nt < 6; nt++)
            #pragma unroll
            for (int r = 0; r < 4; r++)
                s[nt] = fmaf(gelu_fast(acc[nt * 3 + mt][r] + b2v[nt]), xv[nt][r], s[nt]);
    }
    #pragma unroll
    for (int nt = 0; nt < 6; nt++) {
        float v = s[nt];
        v += __shfl_xor(v, 16, 64);
        v += __shfl_xor(v, 32, 64);
        if (lane < 16)
            hbufB[(size_t)bl * ND + wn0 + nt * 16 + lane] = f2bf(v);
    }
}

// ---------------------------------------------------------------------------
// Kernel 2: MLP head via MFMA. One wave (64 thr) per 16 rows.
// layer1: [16x384]@[384x128] bf16 MFMA; gelu -> T1 (LDS, stride 136);
// layer2: [16x128]@[128x64]; gelu; layer3: 64-dot via VALU + shuffles;
// masked per-block partial -> dGpart[block] (no atomics).
// ---------------------------------------------------------------------------
__global__ __launch_bounds__(64) void head_kernel(
    const unsigned short* __restrict__ hbufB,
    const unsigned short* __restrict__ hw1p, const float* __restrict__ hb1,
    const unsigned short* __restrict__ hw2p, const float* __restrict__ hb2,
    const float* __restrict__ hw3, const float* __restrict__ hb3,
    const float* __restrict__ mask, float* __restrict__ dGpart)
{
    __shared__ unsigned short T1[16 * 136];
    const int lane = threadIdx.x;
    const int quad = lane >> 4, l16 = lane & 15;
    const int row0 = blockIdx.x * 16;

    // ---- layer1: K=384, N=128 ----
    f32x4 acc1[8];
    #pragma unroll
    for (int nt = 0; nt < 8; nt++) acc1[nt] = (f32x4){0.f, 0.f, 0.f, 0.f};

    for (int kt = 0; kt < 12; kt++) {
        short8 a = *(const short8*)(hbufB + (size_t)(row0 + l16) * ND + kt * 32 + quad * 8);
        #pragma unroll
        for (int nt = 0; nt < 8; nt++) {
            short8 b = *(const short8*)(hw1p + (size_t)((kt * 8 + nt) * 64 + lane) * 8);
            acc1[nt] = __builtin_amdgcn_mfma_f32_16x16x32_bf16(a, b, acc1[nt], 0, 0, 0);
        }
    }

    // gelu + bias -> T1 bf16
    #pragma unroll
    for (int nt = 0; nt < 8; nt++) {
        int col = nt * 16 + l16;
        float b1 = hb1[col];
        #pragma unroll
        for (int r = 0; r < 4; r++)
            T1[(quad * 4 + r) * 136 + col] = f2bf_rhu(gelu_fast(acc1[nt][r] + b1));
    }
    __syncthreads();

    // ---- layer2: K=128, N=64 ----
    f32x4 acc2[4];
    #pragma unroll
    for (int nt = 0; nt < 4; nt++) acc2[nt] = (f32x4){0.f, 0.f, 0.f, 0.f};

    #pragma unroll
    for (int kt = 0; kt < 4; kt++) {
        short8 a = *(const short8*)&T1[l16 * 136 + kt * 32 + quad * 8];
        #pragma unroll
        for (int nt = 0; nt < 4; nt++) {
            short8 b = *(const short8*)(hw2p + (size_t)((kt * 4 + nt) * 64 + lane) * 8);
            acc2[nt] = __builtin_amdgcn_mfma_f32_16x16x32_bf16(a, b, acc2[nt], 0, 0, 0);
        }
    }

    // ---- layer3: gelu then 64-dot + masked accumulation ----
    float w3[4], b2[4];
    #pragma unroll
    for (int nt = 0; nt < 4; nt++) { w3[nt] = hw3[nt * 16 + l16]; b2[nt] = hb2[nt * 16 + l16]; }

    float dsum = 0.f;
    const float hb3v = hb3[0];
    #pragma unroll
    for (int r = 0; r < 4; r++) {
        float pr = 0.f;
        #pragma unroll
        for (int nt = 0; nt < 4; nt++)
            pr = fmaf(gelu_fast(acc2[nt][r] + b2[nt]), w3[nt], pr);
        pr += __shfl_xor(pr, 1, 64);
        pr += __shfl_xor(pr, 2, 64);
        pr += __shfl_xor(pr, 4, 64);
        pr += __shfl_xor(pr, 8, 64);
        if (l16 == 0) {
            int grow = row0 + quad * 4 + r;
            dsum = fmaf(pr + hb3v, mask[grow], dsum);
        }
    }
    dsum += __shfl_xor(dsum, 16, 64);
    dsum += __shfl_xor(dsum, 32, 64);
    if (lane == 0) dGpart[blockIdx.x] = dsum;
}

// ---------------------------------------------------------------------------
// Kernel 3: out[b] = sum(dGpart[b*32..b*32+32)) / sqrt(clip(sum(mask[b,:]),1))
// 256 threads: 16 lanes per batch
// ---------------------------------------------------------------------------
__global__ void finalize_kernel(const float* __restrict__ dGpart,
                                const float* __restrict__ mask,
                                float* __restrict__ out) {
    int t = threadIdx.x;
    int b = t >> 4, j = t & 15;
    float ms = 0.f;
    for (int l = j; l < NL; l += 16) ms += mask[b * NL + l];
    float dg = dGpart[b * 32 + j] + dGpart[b * 32 + 16 + j];
    #pragma unroll
    for (int d = 1; d < 16; d <<= 1) {
        ms += __shfl_xor(ms, d, 64);
        dg += __shfl_xor(dg, d, 64);
    }
    if (j == 0) {
        ms = fmaxf(ms, 1.0f);
        out[b] = dg / sqrtf(ms);
    }
}

extern "C" void kernel_launch(void* const* d_in, const int* in_sizes, int n_in,
                              void* d_out, int out_size, void* d_ws, size_t ws_size,
                              hipStream_t stream) {
    const float* h_V  = (const float*)d_in[0];
    const float* h_E  = (const float*)d_in[1];
    const float* mask = (const float*)d_in[2];
    const float* fw1  = (const float*)d_in[3];
    const float* fb1  = (const float*)d_in[4];
    const float* fw2  = (const float*)d_in[5];
    const float* fb2  = (const float*)d_in[6];
    const float* hw1  = (const float*)d_in[7];
    const float* hb1  = (const float*)d_in[8];
    const float* hw2  = (const float*)d_in[9];
    const float* hb2  = (const float*)d_in[10];
    const float* hw3  = (const float*)d_in[11];
    const float* hb3  = (const float*)d_in[12];
    const int*   E_idx = (const int*)d_in[13];
    float* out = (float*)d_out;

    char* ws = (char*)d_ws;
    unsigned short* fw1p = (unsigned short*)ws;              // 128*384*2 =  98304 B
    unsigned short* fw2p = (unsigned short*)(ws + 98304);    // 384*384*2 = 294912 B
    unsigned short* hw1p = (unsigned short*)(ws + 393216);   // 384*128*2 =  98304 B
    unsigned short* hw2p = (unsigned short*)(ws + 491520);   // 128*64*2  =  16384 B
    float* dGpart = (float*)(ws + 507904);                   // 512*4 = 2048 B
    unsigned short* hbufB = (unsigned short*)(ws + 512000);  // 8192*384*2 = 6.3 MB

    pack_weights<<<992, 256, 0, stream>>>(fw1, fw2, hw1, hw2, fw1p, fw2p, hw1p, hw2p);
    cfconv_kernel<<<NB * NL, 256, 0, stream>>>(h_V, h_E, fb1, fb2, fw1p, fw2p, E_idx, hbufB);
    head_kernel<<<(NB * NL) / 16, 64, 0, stream>>>(hbufB, hw1p, hb1, hw2p, hb2, hw3, hb3, mask, dGpart);
    finalize_kernel<<<1, 256, 0, stream>>>(dGpart, mask, out);
}